// Round 11
// baseline (226.034 us; speedup 1.0000x reference)
//
#include <hip/hip_runtime.h>
#include <math.h>

// Problem constants (B,T,D,H,HD) = (4,1024,1024,16,64)
constexpr int Bn = 4, Tn = 1024, Dn = 1024, Hn = 16, HDn = 64;

typedef __attribute__((ext_vector_type(8))) short short8;     // 8 bf16 (4 VGPRs)
typedef __attribute__((ext_vector_type(4))) float floatx4;    // MFMA C/D
typedef __attribute__((ext_vector_type(4))) unsigned short ushort4v;

static __device__ __forceinline__ unsigned short f2bf(float f) {
  union { float f; unsigned int u; } v; v.f = f;
  unsigned int u = v.u;
  unsigned int r = (u + 0x7fffu + ((u >> 16) & 1u)) >> 16;   // RNE
  return (unsigned short)r;
}

static __device__ __forceinline__ float bf2f(unsigned short s) {
  union { unsigned int u; float f; } v;
  v.u = ((unsigned int)s) << 16;
  return v.f;
}

// round-half-up bf16 for known-positive finite values (P probabilities)
static __device__ __forceinline__ unsigned short f2bf_fast(float f) {
  union { float f; unsigned int u; } v; v.f = f;
  return (unsigned short)((v.u + 0x8000u) >> 16);
}

static __device__ __forceinline__ void gload_lds16(const void* g, void* l) {
  __builtin_amdgcn_global_load_lds(
      (const __attribute__((address_space(1))) unsigned int*)g,
      (__attribute__((address_space(3))) unsigned int*)l, 16, 0, 0);
}

// NOTE: softmax rows sum to 1 -> importance == 1/T for every head regardless
// of input -> frac = sigmoid(~0) ~ 0.5 -> kv = round(6) -> odd -> 7 ALWAYS.
// The kernel-size MLP inputs are dead; grouped conv uses taps [1..7] of 9.
//
// LESSON (round 6): single-barrier double-buffered global_load_lds (LDS-DMA)
// RACES on graph replay. Do not reintroduce DMA double-buffering.
// LESSON (round 8): direct global->VGPR MFMA fragment loads are lane-
// UNCOALESCED. LDS staging is mandatory for fragment feeding.
// LESSON (round 10): register-staged dbuf is SAFE but NEUTRAL (VALUBusy
// 17->10, dur unchanged) -> the m97-structure stall is the per-phase
// dependency chain, not global-load latency. Amortize phases via fusion
// (QK share the A-tile), don't pipeline them.

// ---------------------------------------------------------------------------
// Merged prep:
//  blocks [0,4096)        : cast x fp32 -> bf16 (row-major copy)
//  blocks [4096,5888)     : repack conv_w (H,64,64,9) fp32 -> Wc (H,7,64,64) bf16
//  blocks [5888,6912)     : transpose-cast Wq/Wk/Wv/fc_w 1024^2 fp32 -> bf16 [n][k]
// ---------------------------------------------------------------------------
__global__ __launch_bounds__(256) void prep_all(
    const float* __restrict__ X, unsigned short* __restrict__ Xb,
    const float* __restrict__ conv_w, unsigned short* __restrict__ Wc,
    const float* __restrict__ W0, const float* __restrict__ W1,
    const float* __restrict__ W2, const float* __restrict__ W3,
    unsigned short* __restrict__ O0, unsigned short* __restrict__ O1,
    unsigned short* __restrict__ O2, unsigned short* __restrict__ O3)
{
  const int tid = threadIdx.x;
  if (blockIdx.x < 4096) {
    int i = (blockIdx.x * 256 + tid) * 4;
    float4 v = *(const float4*)(X + i);
    ushort4v o;
    o.x = f2bf(v.x); o.y = f2bf(v.y); o.z = f2bf(v.z); o.w = f2bf(v.w);
    *(ushort4v*)(Xb + i) = o;
  } else if (blockIdx.x < 5888) {
    int idx = (blockIdx.x - 4096) * 256 + tid;   // ((h*7+j)*64+o)*64+i
    int i = idx & 63;
    int o = (idx >> 6) & 63;
    int j = (idx >> 12) % 7;
    int h = idx / (7 * 4096);
    Wc[idx] = f2bf(conv_w[(((size_t)(h * 64 + o) * 64 + i) * 9) + 1 + j]);
  } else {
    int bid = blockIdx.x - 5888;          // 0..1023
    int z = bid >> 8;
    int rem = bid & 255;
    int cx = rem & 15, ry = rem >> 4;
    const float* W = (z == 0) ? W0 : (z == 1) ? W1 : (z == 2) ? W2 : W3;
    unsigned short* O = (z == 0) ? O0 : (z == 1) ? O1 : (z == 2) ? O2 : O3;
    __shared__ float tile[64][65];
    const int c0 = cx * 64, r0 = ry * 64;
    for (int i = tid; i < 4096; i += 256) {
      int r = i >> 6, c = i & 63;
      tile[r][c] = W[(size_t)(r0 + r) * 1024 + c0 + c];
    }
    __syncthreads();
    for (int i = tid; i < 4096; i += 256) {
      int r = i >> 6, c = i & 63;
      O[(size_t)(c0 + r) * 1024 + r0 + c] = f2bf(tile[c][r]);
    }
  }
}

// ---------------------------------------------------------------------------
// QKV GEMM with Q+K fusion. blockIdx.x < 8: fused Q&K for n-tile (A-tile
// staged once, both Wq/Wk tiles staged; A-fragments reused for both MFMAs ->
// 2x MFMA work per barrier phase, 0.375 LDS reads/MFMA). blockIdx.x >= 8:
// V-only (m97 single-buffer). 128x128 tile, BK=64, 4 waves. grid (16, 32).
// Q,K bf16 (B,H,T,HD); V bf16^T (B,H,HD,T).
// ---------------------------------------------------------------------------
__global__ __launch_bounds__(256) void gemm_qkv_mfma(
    const unsigned short* __restrict__ Ab,
    const unsigned short* __restrict__ WqT, const unsigned short* __restrict__ WkT,
    const unsigned short* __restrict__ WvT,
    const float* __restrict__ bq, const float* __restrict__ bk, const float* __restrict__ bv,
    unsigned short* __restrict__ Qb, unsigned short* __restrict__ Kb,
    unsigned short* __restrict__ Vtb)
{
  __shared__ unsigned short As[128 * 64];    // 16 KB
  __shared__ unsigned short B0s[128 * 64];   // 16 KB
  __shared__ unsigned short B1s[128 * 64];   // 16 KB (fused path only)
  const int tid = threadIdx.x;
  const int lane = tid & 63;
  const int ln = lane & 15, g = lane >> 4;
  const int wave = tid >> 6;
  const int wm = (wave >> 1) * 64, wn = (wave & 1) * 64;
  const int m0 = blockIdx.y * 128;
  const bool fusedQK = blockIdx.x < 8;
  const int n0 = (fusedQK ? blockIdx.x : (blockIdx.x - 8)) * 128;

  // staging addresses (XOR-16B-chunk swizzle)
  const unsigned short* aSrc[4]; unsigned short* aDst[4];
  const unsigned short* b0Src[4]; unsigned short* b0Dst[4];
  const unsigned short* b1Src[4]; unsigned short* b1Dst[4];
  {
    const unsigned short* W0 = fusedQK ? WqT : WvT;
    const unsigned short* W1 = fusedQK ? WkT : WvT;   // unused on V path
    #pragma unroll
    for (int it = 0; it < 4; ++it) {
      int L = it * 256 + tid;
      int r = L >> 3, sc = L & 7;
      int c = sc ^ (r & 7);
      aSrc[it]  = Ab + (size_t)(m0 + r) * 1024 + c * 8;
      aDst[it]  = As + L * 8;
      b0Src[it] = W0 + (size_t)(n0 + r) * 1024 + c * 8;
      b0Dst[it] = B0s + L * 8;
      b1Src[it] = W1 + (size_t)(n0 + r) * 1024 + c * 8;
      b1Dst[it] = B1s + L * 8;
    }
  }

  floatx4 acc0[4][4], acc1[4][4];
  #pragma unroll
  for (int mt = 0; mt < 4; ++mt)
    #pragma unroll
    for (int nt = 0; nt < 4; ++nt) { acc0[mt][nt] = (floatx4)0.f; acc1[mt][nt] = (floatx4)0.f; }

  for (int k0 = 0; k0 < 1024; k0 += 64) {
    __syncthreads();
    #pragma unroll
    for (int it = 0; it < 4; ++it) {
      gload_lds16(aSrc[it] + k0, aDst[it]);
      gload_lds16(b0Src[it] + k0, b0Dst[it]);
    }
    if (fusedQK) {
      #pragma unroll
      for (int it = 0; it < 4; ++it)
        gload_lds16(b1Src[it] + k0, b1Dst[it]);
    }
    __syncthreads();   // vmcnt drain (m97 structure)
    #pragma unroll
    for (int s = 0; s < 2; ++s) {
      short8 af[4], bf[4];
      #pragma unroll
      for (int mt = 0; mt < 4; ++mt) {
        int R = wm + mt * 16 + ln;
        int ch = (s * 4 + g) ^ (R & 7);
        af[mt] = *(const short8*)&As[(R * 8 + ch) * 8];
      }
      #pragma unroll
      for (int nt = 0; nt < 4; ++nt) {
        int R = wn + nt * 16 + ln;
        int ch = (s * 4 + g) ^ (R & 7);
        bf[nt] = *(const short8*)&B0s[(R * 8 + ch) * 8];
      }
      #pragma unroll
      for (int mt = 0; mt < 4; ++mt)
        #pragma unroll
        for (int nt = 0; nt < 4; ++nt)
          acc0[mt][nt] = __builtin_amdgcn_mfma_f32_16x16x32_bf16(af[mt], bf[nt], acc0[mt][nt], 0, 0, 0);
      if (fusedQK) {
        #pragma unroll
        for (int nt = 0; nt < 4; ++nt) {
          int R = wn + nt * 16 + ln;
          int ch = (s * 4 + g) ^ (R & 7);
          bf[nt] = *(const short8*)&B1s[(R * 8 + ch) * 8];
        }
        #pragma unroll
        for (int mt = 0; mt < 4; ++mt)
          #pragma unroll
          for (int nt = 0; nt < 4; ++nt)
            acc1[mt][nt] = __builtin_amdgcn_mfma_f32_16x16x32_bf16(af[mt], bf[nt], acc1[mt][nt], 0, 0, 0);
      }
    }
  }

  const int b = m0 >> 10;
  const int tbase = m0 & 1023;
  if (fusedQK) {
    #pragma unroll
    for (int nt = 0; nt < 4; ++nt) {
      int nl = wn + nt * 16 + ln;
      float bq_ = bq[n0 + nl], bk_ = bk[n0 + nl];
      int h = (n0 + nl) >> 6, hd = (n0 + nl) & 63;
      #pragma unroll
      for (int mt = 0; mt < 4; ++mt) {
        int t = tbase + wm + mt * 16 + g * 4;
        size_t base = (((size_t)b * Hn + h) * Tn + t) * HDn + hd;
        #pragma unroll
        for (int r = 0; r < 4; ++r) {
          Qb[base + (size_t)r * HDn] = f2bf(acc0[mt][nt][r] + bq_);
          Kb[base + (size_t)r * HDn] = f2bf(acc1[mt][nt][r] + bk_);
        }
      }
    }
  } else {
    #pragma unroll
    for (int nt = 0; nt < 4; ++nt) {
      int nl = wn + nt * 16 + ln;
      float bv_ = bv[n0 + nl];
      int h = (n0 + nl) >> 6, hd = (n0 + nl) & 63;
      #pragma unroll
      for (int mt = 0; mt < 4; ++mt) {
        int t = tbase + wm + mt * 16 + g * 4;
        ushort4v o;
        #pragma unroll
        for (int r = 0; r < 4; ++r) o[r] = f2bf(acc0[mt][nt][r] + bv_);
        *(ushort4v*)(Vtb + (((size_t)b * Hn + h) * HDn + hd) * Tn + t) = o;
      }
    }
  }
}

// ---------------------------------------------------------------------------
// MFMA fc GEMM, register-staged double buffer (R10, passing): CO @ fc_w^T +
// bias -> PRb bf16. grid (8, 32).
// ---------------------------------------------------------------------------
__global__ __launch_bounds__(256) void gemm_fc_mfma(
    const unsigned short* __restrict__ Ab, const unsigned short* __restrict__ WT,
    const float* __restrict__ bia, unsigned short* __restrict__ PRb)
{
  __shared__ unsigned short As[2][128 * 64];
  __shared__ unsigned short Bs[2][128 * 64];
  const int tid = threadIdx.x;
  const int lane = tid & 63;
  const int ln = lane & 15, g = lane >> 4;
  const int wave = tid >> 6;
  const int wm = (wave >> 1) * 64, wn = (wave & 1) * 64;
  const int m0 = blockIdx.y * 128;
  const int n0 = blockIdx.x * 128;

  const unsigned short* aSrc[4];
  const unsigned short* bSrc[4];
  int dOff[4];
  #pragma unroll
  for (int it = 0; it < 4; ++it) {
    int L = it * 256 + tid;
    int r = L >> 3, sc = L & 7;
    int c = sc ^ (r & 7);
    aSrc[it] = Ab + (size_t)(m0 + r) * 1024 + c * 8;
    bSrc[it] = WT + (size_t)(n0 + r) * 1024 + c * 8;
    dOff[it] = L * 8;
  }

  short8 aR[4], bR[4];
  #pragma unroll
  for (int it = 0; it < 4; ++it) {
    aR[it] = *(const short8*)(aSrc[it]);
    bR[it] = *(const short8*)(bSrc[it]);
  }
  #pragma unroll
  for (int it = 0; it < 4; ++it) {
    *(short8*)&As[0][dOff[it]] = aR[it];
    *(short8*)&Bs[0][dOff[it]] = bR[it];
  }
  __syncthreads();

  floatx4 acc[4][4];
  #pragma unroll
  for (int mt = 0; mt < 4; ++mt)
    #pragma unroll
    for (int nt = 0; nt < 4; ++nt) acc[mt][nt] = (floatx4)0.f;

  int p = 0;
  for (int k0 = 0; k0 < 1024; k0 += 64) {
    const bool more = (k0 + 64) < 1024;
    if (more) {
      #pragma unroll
      for (int it = 0; it < 4; ++it) {
        aR[it] = *(const short8*)(aSrc[it] + k0 + 64);
        bR[it] = *(const short8*)(bSrc[it] + k0 + 64);
      }
    }
    #pragma unroll
    for (int s = 0; s < 2; ++s) {
      short8 af[4], bf[4];
      #pragma unroll
      for (int mt = 0; mt < 4; ++mt) {
        int R = wm + mt * 16 + ln;
        int ch = (s * 4 + g) ^ (R & 7);
        af[mt] = *(const short8*)&As[p][(R * 8 + ch) * 8];
      }
      #pragma unroll
      for (int nt = 0; nt < 4; ++nt) {
        int R = wn + nt * 16 + ln;
        int ch = (s * 4 + g) ^ (R & 7);
        bf[nt] = *(const short8*)&Bs[p][(R * 8 + ch) * 8];
      }
      #pragma unroll
      for (int mt = 0; mt < 4; ++mt)
        #pragma unroll
        for (int nt = 0; nt < 4; ++nt)
          acc[mt][nt] = __builtin_amdgcn_mfma_f32_16x16x32_bf16(af[mt], bf[nt], acc[mt][nt], 0, 0, 0);
    }
    if (more) {
      const int np = p ^ 1;
      #pragma unroll
      for (int it = 0; it < 4; ++it) {
        *(short8*)&As[np][dOff[it]] = aR[it];
        *(short8*)&Bs[np][dOff[it]] = bR[it];
      }
    }
    __syncthreads();
    p ^= 1;
  }

  #pragma unroll
  for (int nt = 0; nt < 4; ++nt) {
    int n = n0 + wn + nt * 16 + ln;
    float bv_ = bia[n];
    #pragma unroll
    for (int mt = 0; mt < 4; ++mt) {
      int m = m0 + wm + mt * 16 + g * 4;
      unsigned short* base = PRb + (size_t)m * Dn + n;
      #pragma unroll
      for (int r = 0; r < 4; ++r) base[(size_t)r * Dn] = f2bf(acc[mt][nt][r] + bv_);
    }
  }
}

// ---------------------------------------------------------------------------
// MFMA flash attention (R10, passing): simplified softmax, register-staged
// double-buffered K/V. Q-tile 128, 8 waves. grid (8, B*H).
// ---------------------------------------------------------------------------
__global__ __launch_bounds__(512) void attn_mfma(
    const unsigned short* __restrict__ Qb, const unsigned short* __restrict__ Kb,
    const unsigned short* __restrict__ Vtb, unsigned short* __restrict__ AO)
{
  __shared__ unsigned short Ks[2][64 * 64];
  __shared__ unsigned short Vts[2][64 * 64];
  __shared__ unsigned short Ps[128 * 72];

  const int bh = blockIdx.y;
  const int q0 = blockIdx.x * 128;
  const int tid = threadIdx.x;
  const int lane = tid & 63;
  const int ln = lane & 15;
  const int g  = lane >> 4;
  const int wq = (tid >> 6) * 16;

  const unsigned short* Kp  = Kb  + (size_t)bh * Tn * HDn;
  const unsigned short* Vtp = Vtb + (size_t)bh * HDn * Tn;

  const unsigned short* Qrow = Qb + ((size_t)bh * Tn + q0 + wq + ln) * HDn;
  short8 qa0 = *(const short8*)(Qrow + g * 8);
  short8 qa1 = *(const short8*)(Qrow + 32 + g * 8);

  const int r_ = tid >> 3, sc_ = tid & 7;
  const int c_ = sc_ ^ (r_ & 7);
  const unsigned short* kSrc = Kp + (size_t)r_ * HDn + c_ * 8;
  const unsigned short* vSrc = Vtp + (size_t)r_ * Tn + c_ * 8;
  const int dO = tid * 8;

  short8 kR = *(const short8*)(kSrc);
  short8 vR = *(const short8*)(vSrc);
  *(short8*)&Ks[0][dO] = kR;
  *(short8*)&Vts[0][dO] = vR;
  __syncthreads();

  floatx4 o[4];
  #pragma unroll
  for (int dt = 0; dt < 4; ++dt) o[dt] = (floatx4)0.f;
  float l[4] = {0.f, 0.f, 0.f, 0.f};

  constexpr float CEXP = 0.18033688011112042f;   // 0.125 * log2(e)

  int p = 0;
  for (int kt = 0; kt < Tn; kt += 64) {
    const bool more = (kt + 64) < Tn;
    if (more) {
      kR = *(const short8*)(kSrc + (size_t)(kt + 64) * HDn);
      vR = *(const short8*)(vSrc + kt + 64);
    }

    floatx4 s[4];
    #pragma unroll
    for (int nt = 0; nt < 4; ++nt) {
      int R = nt * 16 + ln;
      int ch0 = g ^ (ln & 7), ch1 = (4 + g) ^ (ln & 7);
      short8 kb0 = *(const short8*)&Ks[p][(R * 8 + ch0) * 8];
      short8 kb1 = *(const short8*)&Ks[p][(R * 8 + ch1) * 8];
      s[nt] = (floatx4)0.f;
      s[nt] = __builtin_amdgcn_mfma_f32_16x16x32_bf16(qa0, kb0, s[nt], 0, 0, 0);
      s[nt] = __builtin_amdgcn_mfma_f32_16x16x32_bf16(qa1, kb1, s[nt], 0, 0, 0);
    }

    #pragma unroll
    for (int r = 0; r < 4; ++r) {
      #pragma unroll
      for (int nt = 0; nt < 4; ++nt) {
        float pv = __builtin_amdgcn_exp2f(s[nt][r] * CEXP);
        l[r] += pv;
        Ps[(wq + g * 4 + r) * 72 + nt * 16 + ln] = f2bf_fast(pv);
      }
    }

    short8 pa0 = *(const short8*)&Ps[(wq + ln) * 72 + g * 8];
    short8 pa1 = *(const short8*)&Ps[(wq + ln) * 72 + 32 + g * 8];

    #pragma unroll
    for (int dt = 0; dt < 4; ++dt) {
      int R = dt * 16 + ln;
      int ch0 = g ^ (ln & 7), ch1 = (4 + g) ^ (ln & 7);
      short8 vb0 = *(const short8*)&Vts[p][(R * 8 + ch0) * 8];
      short8 vb1 = *(const short8*)&Vts[p][(R * 8 + ch1) * 8];
      o[dt] = __builtin_amdgcn_mfma_f32_16x16x32_bf16(pa0, vb0, o[dt], 0, 0, 0);
      o[dt] = __builtin_amdgcn_mfma_f32_16x16x32_bf16(pa1, vb1, o[dt], 0, 0, 0);
    }

    if (more) {
      const int np = p ^ 1;
      *(short8*)&Ks[np][dO] = kR;
      *(short8*)&Vts[np][dO] = vR;
    }
    __syncthreads();
    p ^= 1;
  }

  float inv[4];
  #pragma unroll
  for (int r = 0; r < 4; ++r) {
    float rs = l[r];
    rs += __shfl_xor(rs, 1);
    rs += __shfl_xor(rs, 2);
    rs += __shfl_xor(rs, 4);
    rs += __shfl_xor(rs, 8);
    inv[r] = 1.f / rs;
  }
  unsigned short* Op = AO + ((size_t)bh * Tn + q0 + wq) * HDn;
  #pragma unroll
  for (int dt = 0; dt < 4; ++dt)
    #pragma unroll
    for (int r = 0; r < 4; ++r)
      Op[(size_t)(g * 4 + r) * HDn + dt * 16 + ln] = f2bf(o[dt][r] * inv[r]);
}

// ---------------------------------------------------------------------------
// MFMA grouped conv, K=7 (single staging phase, global_load_lds, one barrier).
// grid (8, 2, 64), 256 threads.
// ---------------------------------------------------------------------------
__global__ __launch_bounds__(256) void conv_mfma(
    const unsigned short* __restrict__ Xb, const unsigned short* __restrict__ Wc,
    const float* __restrict__ conv_b, unsigned short* __restrict__ CO)
{
  __shared__ unsigned short Wl[7 * 32 * 64];   // 28672 B
  __shared__ unsigned short Xs[134 * 64];      // 17152 B
  const int tid = threadIdx.x;
  const int lane = tid & 63;
  const int ln = lane & 15, g = lane >> 4;
  const int wave = tid >> 6;
  const int wm = wave * 32;
  const int t0 = blockIdx.x * 128;
  const int o0 = blockIdx.y * 32;
  const int bh = blockIdx.z;
  const int b = bh >> 4, h = bh & 15;
  const unsigned short* Xp = Xb + (size_t)bh * Tn * HDn;
  const unsigned short* Wp = Wc + ((size_t)h * 7 * 64 + o0) * 64;

  #pragma unroll
  for (int it = 0; it < 7; ++it) {
    int L = it * 256 + tid;
    int row = L >> 3, sc = L & 7;
    int c = sc ^ (row & 7);
    int j = row >> 5, ol = row & 31;
    gload_lds16(Wp + ((size_t)j * 64 + ol) * 64 + c * 8, Wl + L * 8);
  }
  #pragma unroll
  for (int it = 0; it < 5; ++it) {
    int L = it * 256 + tid;
    if (L < 134 * 8) {
      int lr = L >> 3, sc = L & 7;
      int c = sc ^ (lr & 7);
      int gr = min(max(t0 - 3 + lr, 0), Tn - 1);
      gload_lds16(Xp + (size_t)gr * HDn + c * 8, Xs + L * 8);
    }
  }
  __syncthreads();

  floatx4 acc[2][2];
  #pragma unroll
  for (int mt = 0; mt < 2; ++mt)
    #pragma unroll
    for (int nt = 0; nt < 2; ++nt) acc[mt][nt] = (floatx4)0.f;

  int tb[2];
  #pragma unroll
  for (int mt = 0; mt < 2; ++mt)
    tb[mt] = min(max(t0 + wm + mt * 16 + ln, 3), Tn - 4) - t0;

  #pragma unroll
  for (int j = 0; j < 7; ++j) {
    #pragma unroll
    for (int s = 0; s < 2; ++s) {
      short8 af[2], bf[2];
      #pragma unroll
      for (int mt = 0; mt < 2; ++mt) {
        int lr = tb[mt] + j;
        int ch = (s * 4 + g) ^ (lr & 7);
        af[mt] = *(const short8*)&Xs[lr * 64 + ch * 8];
      }
      #pragma unroll
      for (int nt = 0; nt < 2; ++nt) {
        int row = j * 32 + nt * 16 + ln;
        int ch = (s * 4 + g) ^ (row & 7);
        bf[nt] = *(const short8*)&Wl[row * 64 + ch * 8];
      }
      #pragma unroll
      for (int mt = 0; mt < 2; ++mt)
        #pragma unroll
        for (int nt = 0; nt < 2; ++nt)
          acc[mt][nt] = __builtin_amdgcn_mfma_f32_16x16x32_bf16(af[mt], bf[nt], acc[mt][nt], 0, 0, 0);
    }
  }

  #pragma unroll
  for (int nt = 0; nt < 2; ++nt) {
    int o = o0 + nt * 16 + ln;
    float bias = conv_b[(h << 6) + o];
    #pragma unroll
    for (int mt = 0; mt < 2; ++mt) {
      int t = t0 + wm + mt * 16 + g * 4;
      #pragma unroll
      for (int r = 0; r < 4; ++r)
        CO[((size_t)b * Tn + t + r) * Dn + (h << 6) + o] = f2bf(acc[mt][nt][r] + bias);
    }
  }
}

// ---------------------------------------------------------------------------
// Residual + LayerNorm; proj bf16 (PRb), x fp32.
// ---------------------------------------------------------------------------
__global__ __launch_bounds__(256) void res_ln(
    const unsigned short* __restrict__ Pb, const float* __restrict__ Xin,
    const float* __restrict__ g, const float* __restrict__ be,
    float* __restrict__ Out)
{
  const int r = blockIdx.x;
  const int tid = threadIdx.x;
  const int c = tid * 4;
  ushort4v pv4 = *(const ushort4v*)(Pb + (size_t)r * Dn + c);
  float4 xv = *(const float4*)(Xin + (size_t)r * Dn + c);
  float v0 = bf2f(pv4.x) + xv.x, v1 = bf2f(pv4.y) + xv.y;
  float v2 = bf2f(pv4.z) + xv.z, v3 = bf2f(pv4.w) + xv.w;
  float s = v0 + v1 + v2 + v3;
  float s2 = v0 * v0 + v1 * v1 + v2 * v2 + v3 * v3;
  #pragma unroll
  for (int off = 32; off > 0; off >>= 1) {
    s += __shfl_down(s, off);
    s2 += __shfl_down(s2, off);
  }
  __shared__ float rs[4], rs2[4];
  __shared__ float smu, srstd;
  const int wid = tid >> 6;
  if ((tid & 63) == 0) { rs[wid] = s; rs2[wid] = s2; }
  __syncthreads();
  if (tid == 0) {
    float S = rs[0] + rs[1] + rs[2] + rs[3];
    float S2 = rs2[0] + rs2[1] + rs2[2] + rs2[3];
    float mu = S * (1.f / Dn);
    float var = S2 * (1.f / Dn) - mu * mu;
    smu = mu;
    srstd = rsqrtf(var + 1e-5f);
  }
  __syncthreads();
  float mu = smu, rstd = srstd;
  float4 gv = *(const float4*)(g + c);
  float4 bv = *(const float4*)(be + c);
  float4 ov;
  ov.x = (v0 - mu) * rstd * gv.x + bv.x;
  ov.y = (v1 - mu) * rstd * gv.y + bv.y;
  ov.z = (v2 - mu) * rstd * gv.z + bv.z;
  ov.w = (v3 - mu) * rstd * gv.w + bv.w;
  *(float4*)(Out + (size_t)r * Dn + c) = ov;
}

extern "C" void kernel_launch(void* const* d_in, const int* in_sizes, int n_in,
                              void* d_out, int out_size, void* d_ws, size_t ws_size,
                              hipStream_t stream) {
  const float* x      = (const float*)d_in[0];
  const float* Wq     = (const float*)d_in[1];
  const float* bq     = (const float*)d_in[2];
  const float* Wk     = (const float*)d_in[3];
  const float* bk     = (const float*)d_in[4];
  const float* Wv     = (const float*)d_in[5];
  const float* bv     = (const float*)d_in[6];
  const float* conv_w = (const float*)d_in[7];
  const float* conv_b = (const float*)d_in[8];
  // d_in[9..12]: kernel-size MLP — provably constant selection (K=7), unused.
  const float* fc_w   = (const float*)d_in[13];
  const float* fc_b   = (const float*)d_in[14];
  const float* ln_g   = (const float*)d_in[15];
  const float* ln_b   = (const float*)d_in[16];
  float* out = (float*)d_out;

  unsigned char* w8 = (unsigned char*)d_ws;
  const size_t MB = 1024 * 1024;
  unsigned short* Xb  = (unsigned short*)(w8);            // [0,8)
  unsigned short* WqT = (unsigned short*)(w8 + 8 * MB);
  unsigned short* WkT = (unsigned short*)(w8 + 10 * MB);
  unsigned short* WvT = (unsigned short*)(w8 + 12 * MB);
  unsigned short* fcT = (unsigned short*)(w8 + 14 * MB);
  unsigned short* Qb  = (unsigned short*)(w8 + 16 * MB);  // [16,24)
  unsigned short* Kb  = (unsigned short*)(w8 + 24 * MB);  // [24,32)
  unsigned short* Vtb = (unsigned short*)(w8 + 32 * MB);  // [32,40)
  unsigned short* AO  = (unsigned short*)(w8 + 40 * MB);  // [40,48)
  unsigned short* Wc  = (unsigned short*)(w8 + 48 * MB);
  unsigned short* CO  = (unsigned short*)(w8);            // overlays Xb (dead)
  unsigned short* PRb = (unsigned short*)(w8 + 16 * MB);  // overlays Qb (dead)

  prep_all<<<dim3(6912), 256, 0, stream>>>(x, Xb, conv_w, Wc,
                                           Wq, Wk, Wv, fc_w, WqT, WkT, WvT, fcT);
  gemm_qkv_mfma<<<dim3(16, 32), 256, 0, stream>>>(Xb, WqT, WkT, WvT, bq, bk, bv, Qb, Kb, Vtb);
  attn_mfma<<<dim3(8, 64), 512, 0, stream>>>(Qb, Kb, Vtb, AO);
  conv_mfma<<<dim3(8, 2, 64), 256, 0, stream>>>(AO, Wc, conv_b, CO);
  gemm_fc_mfma<<<dim3(8, 32), 256, 0, stream>>>(CO, fcT, fc_b, PRb);
  res_ln<<<dim3(Bn * Tn), 256, 0, stream>>>(PRb, x, ln_g, ln_b, out);
}

// Round 12
// 223.579 us; speedup vs baseline: 1.0110x; 1.0110x over previous
//
#include <hip/hip_runtime.h>
#include <math.h>

// Problem constants (B,T,D,H,HD) = (4,1024,1024,16,64)
constexpr int Bn = 4, Tn = 1024, Dn = 1024, Hn = 16, HDn = 64;

typedef __attribute__((ext_vector_type(8))) short short8;     // 8 bf16 (4 VGPRs)
typedef __attribute__((ext_vector_type(4))) float floatx4;    // MFMA C/D
typedef __attribute__((ext_vector_type(4))) unsigned short ushort4v;

static __device__ __forceinline__ unsigned short f2bf(float f) {
  union { float f; unsigned int u; } v; v.f = f;
  unsigned int u = v.u;
  unsigned int r = (u + 0x7fffu + ((u >> 16) & 1u)) >> 16;   // RNE
  return (unsigned short)r;
}

static __device__ __forceinline__ float bf2f(unsigned short s) {
  union { unsigned int u; float f; } v;
  v.u = ((unsigned int)s) << 16;
  return v.f;
}

// round-half-up bf16 for known-positive finite values (P probabilities)
static __device__ __forceinline__ unsigned short f2bf_fast(float f) {
  union { float f; unsigned int u; } v; v.f = f;
  return (unsigned short)((v.u + 0x8000u) >> 16);
}

static __device__ __forceinline__ short8 cvt_f4x2(float4 lo, float4 hi) {
  short8 r;
  r[0] = (short)f2bf(lo.x); r[1] = (short)f2bf(lo.y);
  r[2] = (short)f2bf(lo.z); r[3] = (short)f2bf(lo.w);
  r[4] = (short)f2bf(hi.x); r[5] = (short)f2bf(hi.y);
  r[6] = (short)f2bf(hi.z); r[7] = (short)f2bf(hi.w);
  return r;
}

static __device__ __forceinline__ void gload_lds16(const void* g, void* l) {
  __builtin_amdgcn_global_load_lds(
      (const __attribute__((address_space(1))) unsigned int*)g,
      (__attribute__((address_space(3))) unsigned int*)l, 16, 0, 0);
}

// NOTE: softmax rows sum to 1 -> importance == 1/T for every head regardless
// of input -> frac = sigmoid(~0) ~ 0.5 -> kv = round(6) -> odd -> 7 ALWAYS.
// The kernel-size MLP inputs are dead; grouped conv uses taps [1..7] of 9.
//
// LESSON (round 6): single-barrier double-buffered global_load_lds (LDS-DMA)
// RACES on graph replay. Do not reintroduce DMA double-buffering.
// LESSON (round 8): direct global->VGPR MFMA fragment loads are lane-
// UNCOALESCED. LDS staging is mandatory for fragment feeding.
// LESSON (round 10): register-staged dbuf is SAFE but NEUTRAL -> the m97
// stall is the per-phase dependency chain, not load latency.
// LESSON (round 11): QK-fusion regressed (VGPR 176 -> occupancy halved).
// The ~45us / 578 TF qkv is the structural plateau of this K=1024 shape.

// ---------------------------------------------------------------------------
// Merged prep:
//  blocks [0,1792)     : repack conv_w (H,64,64,9) fp32 -> Wc (H,7,64,64) bf16
//  blocks [1792,2816)  : transpose-cast Wq/Wk/Wv/fc_w 1024^2 fp32 -> bf16 [n][k]
// (x cast is fused into gemm_qkv_mfma's A-staging.)
// ---------------------------------------------------------------------------
__global__ __launch_bounds__(256) void prep_all(
    const float* __restrict__ conv_w, unsigned short* __restrict__ Wc,
    const float* __restrict__ W0, const float* __restrict__ W1,
    const float* __restrict__ W2, const float* __restrict__ W3,
    unsigned short* __restrict__ O0, unsigned short* __restrict__ O1,
    unsigned short* __restrict__ O2, unsigned short* __restrict__ O3)
{
  const int tid = threadIdx.x;
  if (blockIdx.x < 1792) {
    int idx = blockIdx.x * 256 + tid;   // ((h*7+j)*64+o)*64+i
    int i = idx & 63;
    int o = (idx >> 6) & 63;
    int j = (idx >> 12) % 7;
    int h = idx / (7 * 4096);
    Wc[idx] = f2bf(conv_w[(((size_t)(h * 64 + o) * 64 + i) * 9) + 1 + j]);
  } else {
    int bid = blockIdx.x - 1792;          // 0..1023
    int z = bid >> 8;
    int rem = bid & 255;
    int cx = rem & 15, ry = rem >> 4;
    const float* W = (z == 0) ? W0 : (z == 1) ? W1 : (z == 2) ? W2 : W3;
    unsigned short* O = (z == 0) ? O0 : (z == 1) ? O1 : (z == 2) ? O2 : O3;
    __shared__ float tile[64][65];
    const int c0 = cx * 64, r0 = ry * 64;
    for (int i = tid; i < 4096; i += 256) {
      int r = i >> 6, c = i & 63;
      tile[r][c] = W[(size_t)(r0 + r) * 1024 + c0 + c];
    }
    __syncthreads();
    for (int i = tid; i < 4096; i += 256) {
      int r = i >> 6, c = i & 63;
      O[(size_t)(c0 + r) * 1024 + r0 + c] = f2bf(tile[c][r]);
    }
  }
}

// ---------------------------------------------------------------------------
// MFMA QKV GEMM, register-staged double buffer, A staged DIRECTLY from x fp32
// (cast fused into staging; x strips are L2-resident across n-blocks).
// 128x128 tile, BK=64, 4 waves, XOR-16B-chunk swizzle.
// Q,K bf16 (B,H,T,HD); V bf16^T (B,H,HD,T). grid (24, 32).
// ---------------------------------------------------------------------------
__global__ __launch_bounds__(256) void gemm_qkv_mfma(
    const float* __restrict__ X,
    const unsigned short* __restrict__ WqT, const unsigned short* __restrict__ WkT,
    const unsigned short* __restrict__ WvT,
    const float* __restrict__ bq, const float* __restrict__ bk, const float* __restrict__ bv,
    unsigned short* __restrict__ Qb, unsigned short* __restrict__ Kb,
    unsigned short* __restrict__ Vtb)
{
  __shared__ unsigned short As[2][128 * 64];   // 2 x 16 KB
  __shared__ unsigned short Bs[2][128 * 64];   // 2 x 16 KB
  const int tid = threadIdx.x;
  const int lane = tid & 63;
  const int ln = lane & 15, g = lane >> 4;
  const int wave = tid >> 6;
  const int wm = (wave >> 1) * 64, wn = (wave & 1) * 64;
  const int m0 = blockIdx.y * 128;
  const int ng = blockIdx.x * 128;
  const int which = ng >> 10;
  const int n0 = ng & 1023;
  const unsigned short* Wt = (which == 0) ? WqT : (which == 1) ? WkT : WvT;
  const float* bia = (which == 0) ? bq : (which == 1) ? bk : bv;

  const float* aSrcF[4];
  const unsigned short* bSrc[4];
  int dOff[4];
  #pragma unroll
  for (int it = 0; it < 4; ++it) {
    int L = it * 256 + tid;
    int r = L >> 3, sc = L & 7;
    int c = sc ^ (r & 7);
    aSrcF[it] = X + (size_t)(m0 + r) * 1024 + c * 8;
    bSrc[it]  = Wt + (size_t)(n0 + r) * 1024 + c * 8;
    dOff[it] = L * 8;
  }

  // prologue: k0=0 through registers into buffer 0 (convert fp32->bf16 for A)
  float4 aLo[4], aHi[4];
  short8 bR[4];
  #pragma unroll
  for (int it = 0; it < 4; ++it) {
    aLo[it] = *(const float4*)(aSrcF[it]);
    aHi[it] = *(const float4*)(aSrcF[it] + 4);
    bR[it] = *(const short8*)(bSrc[it]);
  }
  #pragma unroll
  for (int it = 0; it < 4; ++it) {
    *(short8*)&As[0][dOff[it]] = cvt_f4x2(aLo[it], aHi[it]);
    *(short8*)&Bs[0][dOff[it]] = bR[it];
  }
  __syncthreads();

  floatx4 acc[4][4];
  #pragma unroll
  for (int mt = 0; mt < 4; ++mt)
    #pragma unroll
    for (int nt = 0; nt < 4; ++nt) acc[mt][nt] = (floatx4)0.f;

  int p = 0;
  for (int k0 = 0; k0 < 1024; k0 += 64) {
    const bool more = (k0 + 64) < 1024;
    if (more) {
      #pragma unroll
      for (int it = 0; it < 4; ++it) {
        aLo[it] = *(const float4*)(aSrcF[it] + k0 + 64);
        aHi[it] = *(const float4*)(aSrcF[it] + k0 + 68);
        bR[it] = *(const short8*)(bSrc[it] + k0 + 64);
      }
    }
    #pragma unroll
    for (int s = 0; s < 2; ++s) {
      short8 af[4], bf[4];
      #pragma unroll
      for (int mt = 0; mt < 4; ++mt) {
        int R = wm + mt * 16 + ln;
        int ch = (s * 4 + g) ^ (R & 7);
        af[mt] = *(const short8*)&As[p][(R * 8 + ch) * 8];
      }
      #pragma unroll
      for (int nt = 0; nt < 4; ++nt) {
        int R = wn + nt * 16 + ln;
        int ch = (s * 4 + g) ^ (R & 7);
        bf[nt] = *(const short8*)&Bs[p][(R * 8 + ch) * 8];
      }
      #pragma unroll
      for (int mt = 0; mt < 4; ++mt)
        #pragma unroll
        for (int nt = 0; nt < 4; ++nt)
          acc[mt][nt] = __builtin_amdgcn_mfma_f32_16x16x32_bf16(af[mt], bf[nt], acc[mt][nt], 0, 0, 0);
    }
    if (more) {
      const int np = p ^ 1;
      #pragma unroll
      for (int it = 0; it < 4; ++it) {
        *(short8*)&As[np][dOff[it]] = cvt_f4x2(aLo[it], aHi[it]);
        *(short8*)&Bs[np][dOff[it]] = bR[it];
      }
    }
    __syncthreads();
    p ^= 1;
  }

  const int b = m0 >> 10;
  const int tbase = m0 & 1023;
  #pragma unroll
  for (int nt = 0; nt < 4; ++nt) {
    int nl = wn + nt * 16 + ln;
    float bv_ = bia[n0 + nl];
    int h = (n0 + nl) >> 6, hd = (n0 + nl) & 63;
    #pragma unroll
    for (int mt = 0; mt < 4; ++mt) {
      int t = tbase + wm + mt * 16 + g * 4;
      if (which < 2) {
        unsigned short* Out = (which == 0) ? Qb : Kb;
        size_t base = (((size_t)b * Hn + h) * Tn + t) * HDn + hd;
        #pragma unroll
        for (int r = 0; r < 4; ++r)
          Out[base + (size_t)r * HDn] = f2bf(acc[mt][nt][r] + bv_);
      } else {
        ushort4v o;
        #pragma unroll
        for (int r = 0; r < 4; ++r) o[r] = f2bf(acc[mt][nt][r] + bv_);
        *(ushort4v*)(Vtb + (((size_t)b * Hn + h) * HDn + hd) * Tn + t) = o;
      }
    }
  }
}

// ---------------------------------------------------------------------------
// MFMA fc GEMM, register-staged double buffer: CO @ fc_w^T + bias -> PRb bf16.
// grid (8, 32).
// ---------------------------------------------------------------------------
__global__ __launch_bounds__(256) void gemm_fc_mfma(
    const unsigned short* __restrict__ Ab, const unsigned short* __restrict__ WT,
    const float* __restrict__ bia, unsigned short* __restrict__ PRb)
{
  __shared__ unsigned short As[2][128 * 64];
  __shared__ unsigned short Bs[2][128 * 64];
  const int tid = threadIdx.x;
  const int lane = tid & 63;
  const int ln = lane & 15, g = lane >> 4;
  const int wave = tid >> 6;
  const int wm = (wave >> 1) * 64, wn = (wave & 1) * 64;
  const int m0 = blockIdx.y * 128;
  const int n0 = blockIdx.x * 128;

  const unsigned short* aSrc[4];
  const unsigned short* bSrc[4];
  int dOff[4];
  #pragma unroll
  for (int it = 0; it < 4; ++it) {
    int L = it * 256 + tid;
    int r = L >> 3, sc = L & 7;
    int c = sc ^ (r & 7);
    aSrc[it] = Ab + (size_t)(m0 + r) * 1024 + c * 8;
    bSrc[it] = WT + (size_t)(n0 + r) * 1024 + c * 8;
    dOff[it] = L * 8;
  }

  short8 aR[4], bR[4];
  #pragma unroll
  for (int it = 0; it < 4; ++it) {
    aR[it] = *(const short8*)(aSrc[it]);
    bR[it] = *(const short8*)(bSrc[it]);
  }
  #pragma unroll
  for (int it = 0; it < 4; ++it) {
    *(short8*)&As[0][dOff[it]] = aR[it];
    *(short8*)&Bs[0][dOff[it]] = bR[it];
  }
  __syncthreads();

  floatx4 acc[4][4];
  #pragma unroll
  for (int mt = 0; mt < 4; ++mt)
    #pragma unroll
    for (int nt = 0; nt < 4; ++nt) acc[mt][nt] = (floatx4)0.f;

  int p = 0;
  for (int k0 = 0; k0 < 1024; k0 += 64) {
    const bool more = (k0 + 64) < 1024;
    if (more) {
      #pragma unroll
      for (int it = 0; it < 4; ++it) {
        aR[it] = *(const short8*)(aSrc[it] + k0 + 64);
        bR[it] = *(const short8*)(bSrc[it] + k0 + 64);
      }
    }
    #pragma unroll
    for (int s = 0; s < 2; ++s) {
      short8 af[4], bf[4];
      #pragma unroll
      for (int mt = 0; mt < 4; ++mt) {
        int R = wm + mt * 16 + ln;
        int ch = (s * 4 + g) ^ (R & 7);
        af[mt] = *(const short8*)&As[p][(R * 8 + ch) * 8];
      }
      #pragma unroll
      for (int nt = 0; nt < 4; ++nt) {
        int R = wn + nt * 16 + ln;
        int ch = (s * 4 + g) ^ (R & 7);
        bf[nt] = *(const short8*)&Bs[p][(R * 8 + ch) * 8];
      }
      #pragma unroll
      for (int mt = 0; mt < 4; ++mt)
        #pragma unroll
        for (int nt = 0; nt < 4; ++nt)
          acc[mt][nt] = __builtin_amdgcn_mfma_f32_16x16x32_bf16(af[mt], bf[nt], acc[mt][nt], 0, 0, 0);
    }
    if (more) {
      const int np = p ^ 1;
      #pragma unroll
      for (int it = 0; it < 4; ++it) {
        *(short8*)&As[np][dOff[it]] = aR[it];
        *(short8*)&Bs[np][dOff[it]] = bR[it];
      }
    }
    __syncthreads();
    p ^= 1;
  }

  #pragma unroll
  for (int nt = 0; nt < 4; ++nt) {
    int n = n0 + wn + nt * 16 + ln;
    float bv_ = bia[n];
    #pragma unroll
    for (int mt = 0; mt < 4; ++mt) {
      int m = m0 + wm + mt * 16 + g * 4;
      unsigned short* base = PRb + (size_t)m * Dn + n;
      #pragma unroll
      for (int r = 0; r < 4; ++r) base[(size_t)r * Dn] = f2bf(acc[mt][nt][r] + bv_);
    }
  }
}

// ---------------------------------------------------------------------------
// MFMA flash attention: simplified softmax (scores bounded -> no running max),
// register-staged double-buffered K/V. Q-tile 128, 8 waves. grid (8, B*H).
// ---------------------------------------------------------------------------
__global__ __launch_bounds__(512) void attn_mfma(
    const unsigned short* __restrict__ Qb, const unsigned short* __restrict__ Kb,
    const unsigned short* __restrict__ Vtb, unsigned short* __restrict__ AO)
{
  __shared__ unsigned short Ks[2][64 * 64];
  __shared__ unsigned short Vts[2][64 * 64];
  __shared__ unsigned short Ps[128 * 72];

  const int bh = blockIdx.y;
  const int q0 = blockIdx.x * 128;
  const int tid = threadIdx.x;
  const int lane = tid & 63;
  const int ln = lane & 15;
  const int g  = lane >> 4;
  const int wq = (tid >> 6) * 16;

  const unsigned short* Kp  = Kb  + (size_t)bh * Tn * HDn;
  const unsigned short* Vtp = Vtb + (size_t)bh * HDn * Tn;

  const unsigned short* Qrow = Qb + ((size_t)bh * Tn + q0 + wq + ln) * HDn;
  short8 qa0 = *(const short8*)(Qrow + g * 8);
  short8 qa1 = *(const short8*)(Qrow + 32 + g * 8);

  const int r_ = tid >> 3, sc_ = tid & 7;
  const int c_ = sc_ ^ (r_ & 7);
  const unsigned short* kSrc = Kp + (size_t)r_ * HDn + c_ * 8;
  const unsigned short* vSrc = Vtp + (size_t)r_ * Tn + c_ * 8;
  const int dO = tid * 8;

  short8 kR = *(const short8*)(kSrc);
  short8 vR = *(const short8*)(vSrc);
  *(short8*)&Ks[0][dO] = kR;
  *(short8*)&Vts[0][dO] = vR;
  __syncthreads();

  floatx4 o[4];
  #pragma unroll
  for (int dt = 0; dt < 4; ++dt) o[dt] = (floatx4)0.f;
  float l[4] = {0.f, 0.f, 0.f, 0.f};

  constexpr float CEXP = 0.18033688011112042f;   // 0.125 * log2(e)

  int p = 0;
  for (int kt = 0; kt < Tn; kt += 64) {
    const bool more = (kt + 64) < Tn;
    if (more) {
      kR = *(const short8*)(kSrc + (size_t)(kt + 64) * HDn);
      vR = *(const short8*)(vSrc + kt + 64);
    }

    floatx4 s[4];
    #pragma unroll
    for (int nt = 0; nt < 4; ++nt) {
      int R = nt * 16 + ln;
      int ch0 = g ^ (ln & 7), ch1 = (4 + g) ^ (ln & 7);
      short8 kb0 = *(const short8*)&Ks[p][(R * 8 + ch0) * 8];
      short8 kb1 = *(const short8*)&Ks[p][(R * 8 + ch1) * 8];
      s[nt] = (floatx4)0.f;
      s[nt] = __builtin_amdgcn_mfma_f32_16x16x32_bf16(qa0, kb0, s[nt], 0, 0, 0);
      s[nt] = __builtin_amdgcn_mfma_f32_16x16x32_bf16(qa1, kb1, s[nt], 0, 0, 0);
    }

    #pragma unroll
    for (int r = 0; r < 4; ++r) {
      #pragma unroll
      for (int nt = 0; nt < 4; ++nt) {
        float pv = __builtin_amdgcn_exp2f(s[nt][r] * CEXP);
        l[r] += pv;
        Ps[(wq + g * 4 + r) * 72 + nt * 16 + ln] = f2bf_fast(pv);
      }
    }

    short8 pa0 = *(const short8*)&Ps[(wq + ln) * 72 + g * 8];
    short8 pa1 = *(const short8*)&Ps[(wq + ln) * 72 + 32 + g * 8];

    #pragma unroll
    for (int dt = 0; dt < 4; ++dt) {
      int R = dt * 16 + ln;
      int ch0 = g ^ (ln & 7), ch1 = (4 + g) ^ (ln & 7);
      short8 vb0 = *(const short8*)&Vts[p][(R * 8 + ch0) * 8];
      short8 vb1 = *(const short8*)&Vts[p][(R * 8 + ch1) * 8];
      o[dt] = __builtin_amdgcn_mfma_f32_16x16x32_bf16(pa0, vb0, o[dt], 0, 0, 0);
      o[dt] = __builtin_amdgcn_mfma_f32_16x16x32_bf16(pa1, vb1, o[dt], 0, 0, 0);
    }

    if (more) {
      const int np = p ^ 1;
      *(short8*)&Ks[np][dO] = kR;
      *(short8*)&Vts[np][dO] = vR;
    }
    __syncthreads();
    p ^= 1;
  }

  float inv[4];
  #pragma unroll
  for (int r = 0; r < 4; ++r) {
    float rs = l[r];
    rs += __shfl_xor(rs, 1);
    rs += __shfl_xor(rs, 2);
    rs += __shfl_xor(rs, 4);
    rs += __shfl_xor(rs, 8);
    inv[r] = 1.f / rs;
  }
  unsigned short* Op = AO + ((size_t)bh * Tn + q0 + wq) * HDn;
  #pragma unroll
  for (int dt = 0; dt < 4; ++dt)
    #pragma unroll
    for (int r = 0; r < 4; ++r)
      Op[(size_t)(g * 4 + r) * HDn + dt * 16 + ln] = f2bf(o[dt][r] * inv[r]);
}

// ---------------------------------------------------------------------------
// MFMA grouped conv, K=7 (single staging phase, global_load_lds, one barrier).
// grid (8, 2, 64), 256 threads.
// ---------------------------------------------------------------------------
__global__ __launch_bounds__(256) void conv_mfma(
    const unsigned short* __restrict__ Xb, const unsigned short* __restrict__ Wc,
    const float* __restrict__ conv_b, unsigned short* __restrict__ CO)
{
  __shared__ unsigned short Wl[7 * 32 * 64];   // 28672 B
  __shared__ unsigned short Xs[134 * 64];      // 17152 B
  const int tid = threadIdx.x;
  const int lane = tid & 63;
  const int ln = lane & 15, g = lane >> 4;
  const int wave = tid >> 6;
  const int wm = wave * 32;
  const int t0 = blockIdx.x * 128;
  const int o0 = blockIdx.y * 32;
  const int bh = blockIdx.z;
  const int b = bh >> 4, h = bh & 15;
  const unsigned short* Xp = Xb + (size_t)bh * Tn * HDn;
  const unsigned short* Wp = Wc + ((size_t)h * 7 * 64 + o0) * 64;

  #pragma unroll
  for (int it = 0; it < 7; ++it) {
    int L = it * 256 + tid;
    int row = L >> 3, sc = L & 7;
    int c = sc ^ (row & 7);
    int j = row >> 5, ol = row & 31;
    gload_lds16(Wp + ((size_t)j * 64 + ol) * 64 + c * 8, Wl + L * 8);
  }
  #pragma unroll
  for (int it = 0; it < 5; ++it) {
    int L = it * 256 + tid;
    if (L < 134 * 8) {
      int lr = L >> 3, sc = L & 7;
      int c = sc ^ (lr & 7);
      int gr = min(max(t0 - 3 + lr, 0), Tn - 1);
      gload_lds16(Xp + (size_t)gr * HDn + c * 8, Xs + L * 8);
    }
  }
  __syncthreads();

  floatx4 acc[2][2];
  #pragma unroll
  for (int mt = 0; mt < 2; ++mt)
    #pragma unroll
    for (int nt = 0; nt < 2; ++nt) acc[mt][nt] = (floatx4)0.f;

  int tb[2];
  #pragma unroll
  for (int mt = 0; mt < 2; ++mt)
    tb[mt] = min(max(t0 + wm + mt * 16 + ln, 3), Tn - 4) - t0;

  #pragma unroll
  for (int j = 0; j < 7; ++j) {
    #pragma unroll
    for (int s = 0; s < 2; ++s) {
      short8 af[2], bf[2];
      #pragma unroll
      for (int mt = 0; mt < 2; ++mt) {
        int lr = tb[mt] + j;
        int ch = (s * 4 + g) ^ (lr & 7);
        af[mt] = *(const short8*)&Xs[lr * 64 + ch * 8];
      }
      #pragma unroll
      for (int nt = 0; nt < 2; ++nt) {
        int row = j * 32 + nt * 16 + ln;
        int ch = (s * 4 + g) ^ (row & 7);
        bf[nt] = *(const short8*)&Wl[row * 64 + ch * 8];
      }
      #pragma unroll
      for (int mt = 0; mt < 2; ++mt)
        #pragma unroll
        for (int nt = 0; nt < 2; ++nt)
          acc[mt][nt] = __builtin_amdgcn_mfma_f32_16x16x32_bf16(af[mt], bf[nt], acc[mt][nt], 0, 0, 0);
    }
  }

  #pragma unroll
  for (int nt = 0; nt < 2; ++nt) {
    int o = o0 + nt * 16 + ln;
    float bias = conv_b[(h << 6) + o];
    #pragma unroll
    for (int mt = 0; mt < 2; ++mt) {
      int t = t0 + wm + mt * 16 + g * 4;
      #pragma unroll
      for (int r = 0; r < 4; ++r)
        CO[((size_t)b * Tn + t + r) * Dn + (h << 6) + o] = f2bf(acc[mt][nt][r] + bias);
    }
  }
}

// ---------------------------------------------------------------------------
// Residual + LayerNorm; proj bf16 (PRb), x fp32.
// ---------------------------------------------------------------------------
__global__ __launch_bounds__(256) void res_ln(
    const unsigned short* __restrict__ Pb, const float* __restrict__ Xin,
    const float* __restrict__ g, const float* __restrict__ be,
    float* __restrict__ Out)
{
  const int r = blockIdx.x;
  const int tid = threadIdx.x;
  const int c = tid * 4;
  ushort4v pv4 = *(const ushort4v*)(Pb + (size_t)r * Dn + c);
  float4 xv = *(const float4*)(Xin + (size_t)r * Dn + c);
  float v0 = bf2f(pv4.x) + xv.x, v1 = bf2f(pv4.y) + xv.y;
  float v2 = bf2f(pv4.z) + xv.z, v3 = bf2f(pv4.w) + xv.w;
  float s = v0 + v1 + v2 + v3;
  float s2 = v0 * v0 + v1 * v1 + v2 * v2 + v3 * v3;
  #pragma unroll
  for (int off = 32; off > 0; off >>= 1) {
    s += __shfl_down(s, off);
    s2 += __shfl_down(s2, off);
  }
  __shared__ float rs[4], rs2[4];
  __shared__ float smu, srstd;
  const int wid = tid >> 6;
  if ((tid & 63) == 0) { rs[wid] = s; rs2[wid] = s2; }
  __syncthreads();
  if (tid == 0) {
    float S = rs[0] + rs[1] + rs[2] + rs[3];
    float S2 = rs2[0] + rs2[1] + rs2[2] + rs2[3];
    float mu = S * (1.f / Dn);
    float var = S2 * (1.f / Dn) - mu * mu;
    smu = mu;
    srstd = rsqrtf(var + 1e-5f);
  }
  __syncthreads();
  float mu = smu, rstd = srstd;
  float4 gv = *(const float4*)(g + c);
  float4 bv = *(const float4*)(be + c);
  float4 ov;
  ov.x = (v0 - mu) * rstd * gv.x + bv.x;
  ov.y = (v1 - mu) * rstd * gv.y + bv.y;
  ov.z = (v2 - mu) * rstd * gv.z + bv.z;
  ov.w = (v3 - mu) * rstd * gv.w + bv.w;
  *(float4*)(Out + (size_t)r * Dn + c) = ov;
}

extern "C" void kernel_launch(void* const* d_in, const int* in_sizes, int n_in,
                              void* d_out, int out_size, void* d_ws, size_t ws_size,
                              hipStream_t stream) {
  const float* x      = (const float*)d_in[0];
  const float* Wq     = (const float*)d_in[1];
  const float* bq     = (const float*)d_in[2];
  const float* Wk     = (const float*)d_in[3];
  const float* bk     = (const float*)d_in[4];
  const float* Wv     = (const float*)d_in[5];
  const float* bv     = (const float*)d_in[6];
  const float* conv_w = (const float*)d_in[7];
  const float* conv_b = (const float*)d_in[8];
  // d_in[9..12]: kernel-size MLP — provably constant selection (K=7), unused.
  const float* fc_w   = (const float*)d_in[13];
  const float* fc_b   = (const float*)d_in[14];
  const float* ln_g   = (const float*)d_in[15];
  const float* ln_b   = (const float*)d_in[16];
  float* out = (float*)d_out;

  unsigned char* w8 = (unsigned char*)d_ws;
  const size_t MB = 1024 * 1024;
  unsigned short* WqT = (unsigned short*)(w8 + 8 * MB);
  unsigned short* WkT = (unsigned short*)(w8 + 10 * MB);
  unsigned short* WvT = (unsigned short*)(w8 + 12 * MB);
  unsigned short* fcT = (unsigned short*)(w8 + 14 * MB);
  unsigned short* Qb  = (unsigned short*)(w8 + 16 * MB);  // [16,24)
  unsigned short* Kb  = (unsigned short*)(w8 + 24 * MB);  // [24,32)
  unsigned short* Vtb = (unsigned short*)(w8 + 32 * MB);  // [32,40)
  unsigned short* AO  = (unsigned short*)(w8 + 40 * MB);  // [40,48)
  unsigned short* Wc  = (unsigned short*)(w8 + 48 * MB);
  unsigned short* CO  = (unsigned short*)(w8);            // [0,8)
  unsigned short* PRb = (unsigned short*)(w8 + 16 * MB);  // overlays Qb (dead)

  prep_all<<<dim3(2816), 256, 0, stream>>>(conv_w, Wc,
                                           Wq, Wk, Wv, fc_w, WqT, WkT, WvT, fcT);
  gemm_qkv_mfma<<<dim3(24, 32), 256, 0, stream>>>(x, WqT, WkT, WvT, bq, bk, bv, Qb, Kb, Vtb);
  attn_mfma<<<dim3(8, 64), 512, 0, stream>>>(Qb, Kb, Vtb, AO);
  conv_mfma<<<dim3(8, 2, 64), 256, 0, stream>>>(AO, Wc, conv_b, CO);
  gemm_fc_mfma<<<dim3(8, 32), 256, 0, stream>>>(CO, fcT, fc_b, PRb);
  res_ln<<<dim3(Bn * Tn), 256, 0, stream>>>(PRb, x, ln_g, ln_b, out);
}